// Round 2
// baseline (979.829 us; speedup 1.0000x reference)
//
#include <hip/hip_runtime.h>
#include <math.h>

#define N_NODES 100000
#define N_EDGES 3200000
#define N_FEAT  500
#define NF4     125      // N_FEAT / 4
#define N_HID   16
#define N_CLS   7
#define NB_SCAN 391      // ceil(100000/256)

// ---------------- workspace layout (element offsets, all 4-byte) ------------
// dinv    : 100000 f
// deg     : 100000 i
// row_ptr : 100001 i   (exclusive prefix of deg; [N] = N_EDGES)
// cursor  : 100000 i
// bsum    : 512    i
// csr_src : 3200000 i  (edge src ids, grouped by dst)
// m1      : 1600000 f  (x @ W1)
// h       : 1600000 f  (relu(agg1 + b1))
// m2      : 700000  f  (h @ W2)
#define OFF_DINV 0
#define OFF_DEG  100000
#define OFF_ROWP 200000
#define OFF_CURS 300004
#define OFF_BSUM 400004
#define OFF_CSR  400516
#define OFF_M1   3600516
#define OFF_H    5200516
#define OFF_M2   6800516
// total 7,500,516 elems = 30.0 MB

// ---------------------------------------------------------------- zero deg
__global__ void zero_deg(int* __restrict__ deg) {
    int i = blockIdx.x * 256 + threadIdx.x;
    if (i < N_NODES) deg[i] = 0;
}

// ---------------------------------------------------------------- degree
__global__ void deg_count(const int* __restrict__ dst, int* __restrict__ deg) {
    int e = blockIdx.x * 256 + threadIdx.x;
    if (e < N_EDGES) atomicAdd(&deg[dst[e]], 1);
}

// ------------------------------------------------- scan step 1 (+ dinv fuse)
// Per-block exclusive scan of deg into row_ptr; block totals to bsum.
__global__ void scan1(const int* __restrict__ deg, int* __restrict__ row_ptr,
                      int* __restrict__ bsum, float* __restrict__ dinv) {
    __shared__ int s[256];
    int t = threadIdx.x;
    int i = blockIdx.x * 256 + t;
    int v = (i < N_NODES) ? deg[i] : 0;
    if (i < N_NODES) dinv[i] = rsqrtf((float)v + 1.0f);  // +1 = self loop
    s[t] = v;
    __syncthreads();
    for (int off = 1; off < 256; off <<= 1) {
        int a = (t >= off) ? s[t - off] : 0;
        __syncthreads();
        s[t] += a;
        __syncthreads();
    }
    if (i < N_NODES) row_ptr[i] = s[t] - v;       // exclusive within block
    if (t == 255) bsum[blockIdx.x] = s[255];      // block total
}

// ------------------------------------------------- scan step 2 (block sums)
__global__ void scan2(int* __restrict__ bsum) {
    __shared__ int s[512];
    int t = threadIdx.x;
    int v = (t < NB_SCAN) ? bsum[t] : 0;
    s[t] = v;
    __syncthreads();
    for (int off = 1; off < 512; off <<= 1) {
        int a = (t >= off) ? s[t - off] : 0;
        __syncthreads();
        s[t] += a;
        __syncthreads();
    }
    if (t < NB_SCAN) bsum[t] = s[t] - v;          // exclusive
}

// ------------------------------------------------- scan step 3 (+ cursor copy)
__global__ void scan3(int* __restrict__ row_ptr, int* __restrict__ cursor,
                      const int* __restrict__ bsum) {
    int i = blockIdx.x * 256 + threadIdx.x;
    if (i < N_NODES) {
        int v = row_ptr[i] + bsum[i >> 8];
        row_ptr[i] = v;
        cursor[i] = v;
    } else if (i == N_NODES) {
        row_ptr[i] = N_EDGES;
    }
}

// ---------------------------------------------------------------- CSR fill
__global__ void fill_csr(const int* __restrict__ src, const int* __restrict__ dst,
                         int* __restrict__ cursor, int* __restrict__ csr) {
    int e = blockIdx.x * 256 + threadIdx.x;
    if (e < N_EDGES) {
        int d = dst[e];
        int pos = atomicAdd(&cursor[d], 1);
        csr[pos] = src[e];
    }
}

// ---------------------------------------------------------------- m1 = x @ W1
// One wave per row; lane l covers float4 chunks {l, l+64}; W1 transposed in
// LDS (504-dword stride, contiguous ds_read_b128); 64-lane butterfly reduce.
__global__ void gemm1(const float* __restrict__ x, const float* __restrict__ W1,
                      float* __restrict__ m1) {
    __shared__ __align__(16) float Wt[16 * 504];
    for (int i = threadIdx.x; i < N_FEAT * N_HID; i += 256) {
        int k = i >> 4, j = i & 15;
        Wt[j * 504 + k] = W1[i];
    }
    __syncthreads();

    int wave = threadIdx.x >> 6;
    int lane = threadIdx.x & 63;
    int row  = blockIdx.x * 4 + wave;
    if (row >= N_NODES) return;

    const float4* x4 = (const float4*)x;
    float acc[16];
#pragma unroll
    for (int j = 0; j < 16; ++j) acc[j] = 0.f;

#pragma unroll
    for (int it = 0; it < 2; ++it) {
        int m = it * 64 + lane;
        if (m < NF4) {
            float4 xv = x4[(size_t)row * NF4 + m];
#pragma unroll
            for (int j = 0; j < 16; ++j) {
                const float4 wv = *(const float4*)&Wt[j * 504 + 4 * m];
                acc[j] += xv.x * wv.x + xv.y * wv.y + xv.z * wv.z + xv.w * wv.w;
            }
        }
    }
#pragma unroll
    for (int off = 32; off > 0; off >>= 1) {
#pragma unroll
        for (int j = 0; j < 16; ++j) acc[j] += __shfl_xor(acc[j], off, 64);
    }
    if (lane == 0) {
        float4* o = (float4*)&m1[(size_t)row * 16];
        o[0] = make_float4(acc[0],  acc[1],  acc[2],  acc[3]);
        o[1] = make_float4(acc[4],  acc[5],  acc[6],  acc[7]);
        o[2] = make_float4(acc[8],  acc[9],  acc[10], acc[11]);
        o[3] = make_float4(acc[12], acc[13], acc[14], acc[15]);
    }
}

// ------------------------------------------- gather layer 1 + bias + ReLU
// Thread per (node, feature); 16 lanes of a node read one 64B m1 row segment.
__global__ void gather1(const int* __restrict__ row_ptr, const int* __restrict__ csr,
                        const float* __restrict__ dinv, const float* __restrict__ m1,
                        const float* __restrict__ b1, float* __restrict__ h) {
    int gt = blockIdx.x * 256 + threadIdx.x;
    int n = gt >> 4, j = gt & 15;
    if (n >= N_NODES) return;
    int beg = row_ptr[n], end = row_ptr[n + 1];
    float acc = 0.f;
    for (int p = beg; p < end; ++p) {
        int s = csr[p];
        acc += m1[(size_t)s * 16 + j] * dinv[s];
    }
    float di = dinv[n];
    float v = (acc + m1[(size_t)n * 16 + j] * di) * di + b1[j];
    h[(size_t)n * 16 + j] = v > 0.f ? v : 0.f;
}

// ---------------------------------------------------------------- m2 = h @ W2
__global__ void gemm2(const float* __restrict__ h, const float* __restrict__ W2,
                      float* __restrict__ m2) {
    __shared__ float sW2[N_HID * N_CLS];
    if (threadIdx.x < N_HID * N_CLS) sW2[threadIdx.x] = W2[threadIdx.x];
    __syncthreads();
    int n = blockIdx.x * 256 + threadIdx.x;
    if (n >= N_NODES) return;
    const float4* h4 = (const float4*)&h[(size_t)n * 16];
    float4 a = h4[0], b = h4[1], c = h4[2], d = h4[3];
    float hh[16] = {a.x,a.y,a.z,a.w, b.x,b.y,b.z,b.w, c.x,c.y,c.z,c.w, d.x,d.y,d.z,d.w};
#pragma unroll
    for (int cc = 0; cc < N_CLS; ++cc) {
        float acc = 0.f;
#pragma unroll
        for (int j = 0; j < N_HID; ++j) acc += hh[j] * sW2[j * N_CLS + cc];
        m2[(size_t)n * N_CLS + cc] = acc;
    }
}

// -------------------------------- gather layer 2 + bias + log-softmax fused
// 8 lanes per node (lane 7 idle in gather, participates in reductions).
__global__ void gather2(const int* __restrict__ row_ptr, const int* __restrict__ csr,
                        const float* __restrict__ dinv, const float* __restrict__ m2,
                        const float* __restrict__ b2, float* __restrict__ out) {
    int gt = blockIdx.x * 256 + threadIdx.x;
    int n = gt >> 3, j = gt & 7;
    if (n >= N_NODES) return;
    bool valid = j < N_CLS;
    float acc = 0.f;
    if (valid) {
        int beg = row_ptr[n], end = row_ptr[n + 1];
        for (int p = beg; p < end; ++p) {
            int s = csr[p];
            acc += m2[(size_t)s * N_CLS + j] * dinv[s];
        }
    }
    float di = dinv[n];
    float v = -1e30f;
    if (valid) v = (acc + m2[(size_t)n * N_CLS + j] * di) * di + b2[j];
    float mx = v;
#pragma unroll
    for (int off = 1; off < 8; off <<= 1) mx = fmaxf(mx, __shfl_xor(mx, off, 8));
    float ex = valid ? expf(v - mx) : 0.f;
    float sum = ex;
#pragma unroll
    for (int off = 1; off < 8; off <<= 1) sum += __shfl_xor(sum, off, 8);
    float ls = mx + logf(sum);
    if (valid) out[(size_t)n * N_CLS + j] = v - ls;
}

// ----------------------------------------------------------------
extern "C" void kernel_launch(void* const* d_in, const int* in_sizes, int n_in,
                              void* d_out, int out_size, void* d_ws, size_t ws_size,
                              hipStream_t stream) {
    const float* x  = (const float*)d_in[0];
    const int*   ei = (const int*)d_in[1];
    const float* W1 = (const float*)d_in[2];
    const float* b1 = (const float*)d_in[3];
    const float* W2 = (const float*)d_in[4];
    const float* b2 = (const float*)d_in[5];
    float* out = (float*)d_out;
    char*  wsb = (char*)d_ws;   // needs 30.0 MB

    const int* src = ei;              // edge_index[0]
    const int* dst = ei + N_EDGES;    // edge_index[1]

    float* dinv   = (float*)(wsb) + OFF_DINV;
    int*   deg    = (int*  )(wsb) + OFF_DEG;
    int*   rowp   = (int*  )(wsb) + OFF_ROWP;
    int*   cursor = (int*  )(wsb) + OFF_CURS;
    int*   bsum   = (int*  )(wsb) + OFF_BSUM;
    int*   csr    = (int*  )(wsb) + OFF_CSR;
    float* m1     = (float*)(wsb) + OFF_M1;
    float* h      = (float*)(wsb) + OFF_H;
    float* m2     = (float*)(wsb) + OFF_M2;

    zero_deg <<<NB_SCAN, 256, 0, stream>>>(deg);
    deg_count<<<N_EDGES / 256, 256, 0, stream>>>(dst, deg);
    scan1    <<<NB_SCAN, 256, 0, stream>>>(deg, rowp, bsum, dinv);
    scan2    <<<1, 512, 0, stream>>>(bsum);
    scan3    <<<NB_SCAN + 1, 256, 0, stream>>>(rowp, cursor, bsum);
    fill_csr <<<N_EDGES / 256, 256, 0, stream>>>(src, dst, cursor, csr);
    gemm1    <<<(N_NODES + 3) / 4, 256, 0, stream>>>(x, W1, m1);
    gather1  <<<N_NODES * 16 / 256, 256, 0, stream>>>(rowp, csr, dinv, m1, b1, h);
    gemm2    <<<NB_SCAN, 256, 0, stream>>>(h, W2, m2);
    gather2  <<<N_NODES * 8 / 256, 256, 0, stream>>>(rowp, csr, dinv, m2, b2, out);
}

// Round 3
// 968.906 us; speedup vs baseline: 1.0113x; 1.0113x over previous
//
#include <hip/hip_runtime.h>
#include <math.h>

#define N_NODES 100000
#define N_EDGES 3200000
#define N_FEAT  500
#define NF4     125      // N_FEAT / 4
#define N_HID   16
#define N_CLS   7

#define BKT_SHIFT 7
#define BKT_SIZE  128
#define NBKT      782            // ceil(100000/128)
#define NBLK_BIN  256            // edge-chunk blocks for hist/binpass
#define EDGES_PER_BLK 12500      // 256 * 12500 = 3.2M exactly
#define COUNTS_LEN (NBKT * NBLK_BIN)   // 200192
#define NBLK_SCANA (COUNTS_LEN / 256)  // 782 exactly

// ---------------- workspace layout (element offsets, 4-byte units) ----------
#define OFF_DINV   0            // 100000 f
#define OFF_COUNTS 100000       // 200192 i (per-(bucket,block) run starts)
#define OFF_BSUM   300192       // 1024 i
#define OFF_BINNED 301216       // 3200000 u32 (src | dst_local<<17), bucket-major
#define OFF_NORM   3501216      // 3200000 f (dinv[src]*dinv[dst] per binned slot)
#define OFF_M1     6701216      // 1600000 f
#define OFF_M2     8301216      // 700000 f
// total 9,001,216 elems = 36.0 MB

// ------------------------------------------------------------- pass 1: hist
__global__ void hist(const int* __restrict__ dst, int* __restrict__ counts) {
    __shared__ int cnt[NBKT];
    int t = threadIdx.x, b = blockIdx.x;
    for (int i = t; i < NBKT; i += 256) cnt[i] = 0;
    __syncthreads();
    int e0 = b * EDGES_PER_BLK;
    for (int e = e0 + t; e < e0 + EDGES_PER_BLK; e += 256)
        atomicAdd(&cnt[dst[e] >> BKT_SHIFT], 1);
    __syncthreads();
    for (int i = t; i < NBKT; i += 256)
        counts[i * NBLK_BIN + b] = cnt[i];
}

// ------------------------------------------------------------- scan chain
__global__ void scanA(int* __restrict__ counts, int* __restrict__ bsum) {
    __shared__ int s[256];
    int t = threadIdx.x;
    int i = blockIdx.x * 256 + t;
    int v = counts[i];                 // COUNTS_LEN is an exact multiple of 256
    s[t] = v;
    __syncthreads();
    for (int off = 1; off < 256; off <<= 1) {
        int a = (t >= off) ? s[t - off] : 0;
        __syncthreads();
        s[t] += a;
        __syncthreads();
    }
    counts[i] = s[t] - v;              // exclusive within block
    if (t == 255) bsum[blockIdx.x] = s[255];
}

__global__ void scanB(int* __restrict__ bsum) {
    __shared__ int s[1024];
    int t = threadIdx.x;
    int v = (t < NBLK_SCANA) ? bsum[t] : 0;
    s[t] = v;
    __syncthreads();
    for (int off = 1; off < 1024; off <<= 1) {
        int a = (t >= off) ? s[t - off] : 0;
        __syncthreads();
        s[t] += a;
        __syncthreads();
    }
    if (t < NBLK_SCANA) bsum[t] = s[t] - v;   // exclusive
}

__global__ void scanC(int* __restrict__ counts, const int* __restrict__ bsum) {
    int i = blockIdx.x * 256 + threadIdx.x;
    counts[i] += bsum[i >> 8];
}

// ------------------------------------------------------------- pass 2: bin
// Each block writes its edges into per-(bucket,block) contiguous runs.
__global__ void binpass(const int* __restrict__ src, const int* __restrict__ dst,
                        const int* __restrict__ counts, unsigned int* __restrict__ binned) {
    __shared__ int cur[NBKT];
    int t = threadIdx.x, b = blockIdx.x;
    for (int i = t; i < NBKT; i += 256) cur[i] = counts[i * NBLK_BIN + b];
    __syncthreads();
    int e0 = b * EDGES_PER_BLK;
    for (int e = e0 + t; e < e0 + EDGES_PER_BLK; e += 256) {
        int d = dst[e];
        int pos = atomicAdd(&cur[d >> BKT_SHIFT], 1);
        binned[pos] = (unsigned int)src[e] | ((unsigned int)(d & (BKT_SIZE - 1)) << 17);
    }
}

// ---------------------------------------------- per-bucket degrees -> dinv
__global__ void bucketdeg(const unsigned int* __restrict__ binned,
                          const int* __restrict__ counts, float* __restrict__ dinv) {
    __shared__ int cnt[BKT_SIZE];
    int t = threadIdx.x, b = blockIdx.x;
    if (t < BKT_SIZE) cnt[t] = 0;
    __syncthreads();
    int beg = counts[b * NBLK_BIN];
    int end = (b < NBKT - 1) ? counts[(b + 1) * NBLK_BIN] : N_EDGES;
    for (int e = beg + t; e < end; e += 256)
        atomicAdd(&cnt[(binned[e] >> 17) & (BKT_SIZE - 1)], 1);
    __syncthreads();
    if (t < BKT_SIZE) {
        int g = b * BKT_SIZE + t;
        if (g < N_NODES) dinv[g] = rsqrtf((float)cnt[t] + 1.0f);  // +1 self loop
    }
}

// ------------------------------------------------------------- norm per edge
__global__ void normfill(const unsigned int* __restrict__ binned,
                         const int* __restrict__ counts, const float* __restrict__ dinv,
                         float* __restrict__ norm) {
    int t = threadIdx.x, b = blockIdx.x;
    int beg = counts[b * NBLK_BIN];
    int end = (b < NBKT - 1) ? counts[(b + 1) * NBLK_BIN] : N_EDGES;
    for (int e = beg + t; e < end; e += 256) {
        unsigned int v = binned[e];
        int s = v & 0x1FFFF;
        int d = b * BKT_SIZE + ((v >> 17) & (BKT_SIZE - 1));
        norm[e] = dinv[s] * dinv[d];
    }
}

// ------------------------------------------------------------- m1 = x @ W1
// W1 lives in registers (chunk-per-lane, 16 float4/lane). Wave pair covers a
// row: half 0 = chunks 0..63, half 1 = chunks 64..124. 17-shuffle halving
// reduction; cross-half combine through 2KB LDS.
#define G1_BLOCKS 512
#define G1_ROWS_PER_BLOCK 196   // 512*196 >= 100000

__global__ __launch_bounds__(256) void gemm1(const float* __restrict__ x,
                                             const float* __restrict__ W1,
                                             float* __restrict__ m1) {
    __shared__ float P[16 * 32];
    const int t = threadIdx.x;
    const int lane = t & 63;
    const int w = t >> 6;
    const int half = w & 1;     // which chunk half
    const int pair = w >> 1;    // which row group of 8
    const int c = half * 64 + lane;   // chunk id

    float4 wr[4][4];
#pragma unroll
    for (int r = 0; r < 4; ++r)
#pragma unroll
        for (int q = 0; q < 4; ++q)
            wr[r][q] = (c < NF4) ? *(const float4*)&W1[(4 * c + r) * 16 + 4 * q]
                                 : make_float4(0.f, 0.f, 0.f, 0.f);
    // feature index this lane ends up holding after the halving reduction
    const int f = ((lane & 1) << 3) | ((lane & 2) << 1) | ((lane & 4) >> 1) | ((lane & 8) >> 3);

    const float4* x4 = (const float4*)x;
    int row0 = blockIdx.x * G1_ROWS_PER_BLOCK;
    int rowend = row0 + G1_ROWS_PER_BLOCK;
    if (rowend > N_NODES) rowend = N_NODES;

    for (int base = row0; base < rowend; base += 16) {
        for (int rr = 0; rr < 8; ++rr) {
            int row = base + pair * 8 + rr;
            float4 xv = make_float4(0.f, 0.f, 0.f, 0.f);
            if (row < rowend && c < NF4) xv = x4[(size_t)row * NF4 + c];
            float a[16];
#pragma unroll
            for (int q = 0; q < 4; ++q) {
                a[4*q+0] = xv.x*wr[0][q].x + xv.y*wr[1][q].x + xv.z*wr[2][q].x + xv.w*wr[3][q].x;
                a[4*q+1] = xv.x*wr[0][q].y + xv.y*wr[1][q].y + xv.z*wr[2][q].y + xv.w*wr[3][q].y;
                a[4*q+2] = xv.x*wr[0][q].z + xv.y*wr[1][q].z + xv.z*wr[2][q].z + xv.w*wr[3][q].z;
                a[4*q+3] = xv.x*wr[0][q].w + xv.y*wr[1][q].w + xv.z*wr[2][q].w + xv.w*wr[3][q].w;
            }
            // halving butterfly: 8+4+2+1+1+1 = 17 shuffles
            bool hb = (lane & 1) != 0;
#pragma unroll
            for (int i = 0; i < 8; ++i) {
                float give = hb ? a[i] : a[i + 8];
                float got = __shfl_xor(give, 1, 64);
                a[i] = (hb ? a[i + 8] : a[i]) + got;
            }
            hb = (lane & 2) != 0;
#pragma unroll
            for (int i = 0; i < 4; ++i) {
                float give = hb ? a[i] : a[i + 4];
                float got = __shfl_xor(give, 2, 64);
                a[i] = (hb ? a[i + 4] : a[i]) + got;
            }
            hb = (lane & 4) != 0;
#pragma unroll
            for (int i = 0; i < 2; ++i) {
                float give = hb ? a[i] : a[i + 2];
                float got = __shfl_xor(give, 4, 64);
                a[i] = (hb ? a[i + 2] : a[i]) + got;
            }
            {
                hb = (lane & 8) != 0;
                float give = hb ? a[0] : a[1];
                float got = __shfl_xor(give, 8, 64);
                a[0] = (hb ? a[1] : a[0]) + got;
            }
            a[0] += __shfl_xor(a[0], 16, 64);
            a[0] += __shfl_xor(a[0], 32, 64);
            if (lane < 16) P[(pair * 8 + rr) * 32 + half * 16 + f] = a[0];
        }
        __syncthreads();
        {
            int rloc = t >> 4, j = t & 15;
            int row = base + rloc;
            if (row < rowend)
                m1[(size_t)row * 16 + j] = P[rloc * 32 + j] + P[rloc * 32 + 16 + j];
        }
        __syncthreads();
    }
}

// ---------------------- layer-1 aggregate + bias + ReLU + h@W2, per bucket
__global__ __launch_bounds__(512) void agg1(const unsigned int* __restrict__ binned,
        const float* __restrict__ norm, const int* __restrict__ counts,
        const float* __restrict__ dinv, const float* __restrict__ m1,
        const float* __restrict__ b1, const float* __restrict__ W2,
        float* __restrict__ m2) {
    __shared__ float acc[BKT_SIZE * 16];
    __shared__ float sW2[N_HID * N_CLS];
    __shared__ float sb1[N_HID];
    int t = threadIdx.x, b = blockIdx.x;
    for (int i = t; i < BKT_SIZE * 16; i += 512) acc[i] = 0.f;
    if (t < N_HID * N_CLS) sW2[t] = W2[t];
    if (t < N_HID) sb1[t] = b1[t];
    __syncthreads();
    int beg = counts[b * NBLK_BIN];
    int end = (b < NBKT - 1) ? counts[(b + 1) * NBLK_BIN] : N_EDGES;
    int j = t & 15, eo = t >> 4;               // 32 edges in flight
    for (int e = beg + eo; e < end; e += 32) {
        unsigned int v = binned[e];
        float nm = norm[e];
        int s = v & 0x1FFFF;
        atomicAdd(&acc[((v >> 17) & (BKT_SIZE - 1)) * 16 + j], m1[(size_t)s * 16 + j] * nm);
    }
    __syncthreads();
    // h = relu(acc + m1[g]*dinv^2 + b1), in place
    for (int idx = t; idx < BKT_SIZE * 16; idx += 512) {
        int n = idx >> 4, jj = idx & 15;
        int g = b * BKT_SIZE + n;
        if (g < N_NODES) {
            float di = dinv[g];
            float hv = acc[idx] + m1[(size_t)g * 16 + jj] * di * di + sb1[jj];
            acc[idx] = hv > 0.f ? hv : 0.f;
        }
    }
    __syncthreads();
    // m2 = h @ W2
    for (int idx = t; idx < BKT_SIZE * N_CLS; idx += 512) {
        int n = idx / 7, cc = idx - n * 7;
        int g = b * BKT_SIZE + n;
        if (g < N_NODES) {
            float sum = 0.f;
#pragma unroll
            for (int jj = 0; jj < N_HID; ++jj) sum += acc[n * 16 + jj] * sW2[jj * 7 + cc];
            m2[(size_t)g * 7 + cc] = sum;
        }
    }
}

// ---------------------- layer-2 aggregate + bias + log-softmax, per bucket
__global__ __launch_bounds__(512) void agg2(const unsigned int* __restrict__ binned,
        const float* __restrict__ norm, const int* __restrict__ counts,
        const float* __restrict__ dinv, const float* __restrict__ m2,
        const float* __restrict__ b2, float* __restrict__ out) {
    __shared__ float acc[BKT_SIZE * 8];
    int t = threadIdx.x, b = blockIdx.x;
    for (int i = t; i < BKT_SIZE * 8; i += 512) acc[i] = 0.f;
    __syncthreads();
    int beg = counts[b * NBLK_BIN];
    int end = (b < NBKT - 1) ? counts[(b + 1) * NBLK_BIN] : N_EDGES;
    int j = t & 7, eo = t >> 3;                // 64 edges in flight
    for (int e = beg + eo; e < end; e += 64) {
        if (j < N_CLS) {
            unsigned int v = binned[e];
            float nm = norm[e];
            int s = v & 0x1FFFF;
            atomicAdd(&acc[((v >> 17) & (BKT_SIZE - 1)) * 8 + j], m2[(size_t)s * 7 + j] * nm);
        }
    }
    __syncthreads();
    for (int pass = 0; pass < 2; ++pass) {
        int n = (t >> 3) + pass * 64;
        int g = b * BKT_SIZE + n;
        bool valid = (g < N_NODES) && (j < N_CLS);
        float v = -1e30f;
        if (valid) {
            float di = dinv[g];
            v = acc[n * 8 + j] + m2[(size_t)g * 7 + j] * di * di + b2[j];
        }
        float mx = v;
#pragma unroll
        for (int off = 1; off < 8; off <<= 1) mx = fmaxf(mx, __shfl_xor(mx, off, 8));
        float ex = valid ? expf(v - mx) : 0.f;
        float sum = ex;
#pragma unroll
        for (int off = 1; off < 8; off <<= 1) sum += __shfl_xor(sum, off, 8);
        float ls = mx + logf(sum);
        if (valid) out[(size_t)g * 7 + j] = v - ls;
    }
}

// ----------------------------------------------------------------
extern "C" void kernel_launch(void* const* d_in, const int* in_sizes, int n_in,
                              void* d_out, int out_size, void* d_ws, size_t ws_size,
                              hipStream_t stream) {
    const float* x  = (const float*)d_in[0];
    const int*   ei = (const int*)d_in[1];
    const float* W1 = (const float*)d_in[2];
    const float* b1 = (const float*)d_in[3];
    const float* W2 = (const float*)d_in[4];
    const float* b2 = (const float*)d_in[5];
    float* out = (float*)d_out;
    char*  wsb = (char*)d_ws;   // needs 36.0 MB

    const int* src = ei;               // edge_index[0]
    const int* dst = ei + N_EDGES;     // edge_index[1]

    float*        dinv   = (float*)(wsb) + OFF_DINV;
    int*          counts = (int*  )(wsb) + OFF_COUNTS;
    int*          bsum   = (int*  )(wsb) + OFF_BSUM;
    unsigned int* binned = (unsigned int*)(wsb) + OFF_BINNED;
    float*        norm   = (float*)(wsb) + OFF_NORM;
    float*        m1     = (float*)(wsb) + OFF_M1;
    float*        m2     = (float*)(wsb) + OFF_M2;

    hist     <<<NBLK_BIN, 256, 0, stream>>>(dst, counts);
    scanA    <<<NBLK_SCANA, 256, 0, stream>>>(counts, bsum);
    scanB    <<<1, 1024, 0, stream>>>(bsum);
    scanC    <<<NBLK_SCANA, 256, 0, stream>>>(counts, bsum);
    binpass  <<<NBLK_BIN, 256, 0, stream>>>(src, dst, counts, binned);
    bucketdeg<<<NBKT, 256, 0, stream>>>(binned, counts, dinv);
    normfill <<<NBKT, 256, 0, stream>>>(binned, counts, dinv, norm);
    gemm1    <<<G1_BLOCKS, 256, 0, stream>>>(x, W1, m1);
    agg1     <<<NBKT, 512, 0, stream>>>(binned, norm, counts, dinv, m1, b1, W2, m2);
    agg2     <<<NBKT, 512, 0, stream>>>(binned, norm, counts, dinv, m2, b2, out);
}

// Round 4
// 965.170 us; speedup vs baseline: 1.0152x; 1.0039x over previous
//
#include <hip/hip_runtime.h>
#include <math.h>

#define N_NODES 100000
#define N_EDGES 3200000
#define N_FEAT  500
#define NF4     125      // N_FEAT / 4
#define N_HID   16
#define N_CLS   7

#define BKT_SHIFT 7
#define BKT_SIZE  128
#define NBKT      782            // ceil(100000/128)
#define NBLK_BIN  256            // edge-chunk blocks for hist/binpass
#define EDGES_PER_BLK 12500      // 256 * 12500 = 3.2M exactly
#define COUNTS_LEN (NBKT * NBLK_BIN)   // 200192
#define NBLK_SCANA (COUNTS_LEN / 256)  // 782 exactly

// ---------------- workspace layout (element offsets, 4-byte units) ----------
#define OFF_DINV   0            // 100000 f
#define OFF_COUNTS 100000       // 200192 i (per-(bucket,block) run starts)
#define OFF_BSUM   300192       // 1024 i
#define OFF_BINNED 301216       // 3200000 u32 (src | dst_local<<17), bucket-major
#define OFF_NORM   3501216      // 3200000 f (dinv[src]*dinv[dst] per binned slot)
#define OFF_M1     6701216      // 1600000 f
#define OFF_M2     8301216      // 800000 f (stride 8, slot 7 = pad)
// total 9,101,216 elems = 36.4 MB

// ------------------------------------------------------------- pass 1: hist
__global__ void hist(const int* __restrict__ dst, int* __restrict__ counts) {
    __shared__ int cnt[NBKT];
    int t = threadIdx.x, b = blockIdx.x;
    for (int i = t; i < NBKT; i += 256) cnt[i] = 0;
    __syncthreads();
    int e0 = b * EDGES_PER_BLK;
    for (int e = e0 + t; e < e0 + EDGES_PER_BLK; e += 256)
        atomicAdd(&cnt[dst[e] >> BKT_SHIFT], 1);
    __syncthreads();
    for (int i = t; i < NBKT; i += 256)
        counts[i * NBLK_BIN + b] = cnt[i];
}

// ------------------------------------------------------------- scan chain
__global__ void scanA(int* __restrict__ counts, int* __restrict__ bsum) {
    __shared__ int s[256];
    int t = threadIdx.x;
    int i = blockIdx.x * 256 + t;
    int v = counts[i];
    s[t] = v;
    __syncthreads();
    for (int off = 1; off < 256; off <<= 1) {
        int a = (t >= off) ? s[t - off] : 0;
        __syncthreads();
        s[t] += a;
        __syncthreads();
    }
    counts[i] = s[t] - v;
    if (t == 255) bsum[blockIdx.x] = s[255];
}

__global__ void scanB(int* __restrict__ bsum) {
    __shared__ int s[1024];
    int t = threadIdx.x;
    int v = (t < NBLK_SCANA) ? bsum[t] : 0;
    s[t] = v;
    __syncthreads();
    for (int off = 1; off < 1024; off <<= 1) {
        int a = (t >= off) ? s[t - off] : 0;
        __syncthreads();
        s[t] += a;
        __syncthreads();
    }
    if (t < NBLK_SCANA) bsum[t] = s[t] - v;
}

__global__ void scanC(int* __restrict__ counts, const int* __restrict__ bsum) {
    int i = blockIdx.x * 256 + threadIdx.x;
    counts[i] += bsum[i >> 8];
}

// ------------------------------------------------------------- pass 2: bin
__global__ void binpass(const int* __restrict__ src, const int* __restrict__ dst,
                        const int* __restrict__ counts, unsigned int* __restrict__ binned) {
    __shared__ int cur[NBKT];
    int t = threadIdx.x, b = blockIdx.x;
    for (int i = t; i < NBKT; i += 256) cur[i] = counts[i * NBLK_BIN + b];
    __syncthreads();
    int e0 = b * EDGES_PER_BLK;
    for (int e = e0 + t; e < e0 + EDGES_PER_BLK; e += 256) {
        int d = dst[e];
        int pos = atomicAdd(&cur[d >> BKT_SHIFT], 1);
        binned[pos] = (unsigned int)src[e] | ((unsigned int)(d & (BKT_SIZE - 1)) << 17);
    }
}

// ---------------------------------------------- per-bucket degrees -> dinv
__global__ void bucketdeg(const unsigned int* __restrict__ binned,
                          const int* __restrict__ counts, float* __restrict__ dinv) {
    __shared__ int cnt[BKT_SIZE];
    int t = threadIdx.x, b = blockIdx.x;
    if (t < BKT_SIZE) cnt[t] = 0;
    __syncthreads();
    int beg = counts[b * NBLK_BIN];
    int end = (b < NBKT - 1) ? counts[(b + 1) * NBLK_BIN] : N_EDGES;
    for (int e = beg + t; e < end; e += 256)
        atomicAdd(&cnt[(binned[e] >> 17) & (BKT_SIZE - 1)], 1);
    __syncthreads();
    if (t < BKT_SIZE) {
        int g = b * BKT_SIZE + t;
        if (g < N_NODES) dinv[g] = rsqrtf((float)cnt[t] + 1.0f);  // +1 self loop
    }
}

// ------------------------------------------------------------- norm per edge
__global__ void normfill(const unsigned int* __restrict__ binned,
                         const int* __restrict__ counts, const float* __restrict__ dinv,
                         float* __restrict__ norm) {
    int t = threadIdx.x, b = blockIdx.x;
    int beg = counts[b * NBLK_BIN];
    int end = (b < NBKT - 1) ? counts[(b + 1) * NBLK_BIN] : N_EDGES;
    for (int e = beg + t; e < end; e += 256) {
        unsigned int v = binned[e];
        int s = v & 0x1FFFF;
        int d = b * BKT_SIZE + ((v >> 17) & (BKT_SIZE - 1));
        norm[e] = dinv[s] * dinv[d];
    }
}

// ------------------------------------------------------------- m1 = x @ W1
#define G1_BLOCKS 512
#define G1_ROWS_PER_BLOCK 196   // 512*196 >= 100000

__global__ __launch_bounds__(256) void gemm1(const float* __restrict__ x,
                                             const float* __restrict__ W1,
                                             float* __restrict__ m1) {
    __shared__ float P[16 * 32];
    const int t = threadIdx.x;
    const int lane = t & 63;
    const int w = t >> 6;
    const int half = w & 1;
    const int pair = w >> 1;
    const int c = half * 64 + lane;

    float4 wr[4][4];
#pragma unroll
    for (int r = 0; r < 4; ++r)
#pragma unroll
        for (int q = 0; q < 4; ++q)
            wr[r][q] = (c < NF4) ? *(const float4*)&W1[(4 * c + r) * 16 + 4 * q]
                                 : make_float4(0.f, 0.f, 0.f, 0.f);
    const int f = ((lane & 1) << 3) | ((lane & 2) << 1) | ((lane & 4) >> 1) | ((lane & 8) >> 3);

    const float4* x4 = (const float4*)x;
    int row0 = blockIdx.x * G1_ROWS_PER_BLOCK;
    int rowend = row0 + G1_ROWS_PER_BLOCK;
    if (rowend > N_NODES) rowend = N_NODES;

    for (int base = row0; base < rowend; base += 16) {
        for (int rr = 0; rr < 8; ++rr) {
            int row = base + pair * 8 + rr;
            float4 xv = make_float4(0.f, 0.f, 0.f, 0.f);
            if (row < rowend && c < NF4) xv = x4[(size_t)row * NF4 + c];
            float a[16];
#pragma unroll
            for (int q = 0; q < 4; ++q) {
                a[4*q+0] = xv.x*wr[0][q].x + xv.y*wr[1][q].x + xv.z*wr[2][q].x + xv.w*wr[3][q].x;
                a[4*q+1] = xv.x*wr[0][q].y + xv.y*wr[1][q].y + xv.z*wr[2][q].y + xv.w*wr[3][q].y;
                a[4*q+2] = xv.x*wr[0][q].z + xv.y*wr[1][q].z + xv.z*wr[2][q].z + xv.w*wr[3][q].z;
                a[4*q+3] = xv.x*wr[0][q].w + xv.y*wr[1][q].w + xv.z*wr[2][q].w + xv.w*wr[3][q].w;
            }
            bool hb = (lane & 1) != 0;
#pragma unroll
            for (int i = 0; i < 8; ++i) {
                float give = hb ? a[i] : a[i + 8];
                float got = __shfl_xor(give, 1, 64);
                a[i] = (hb ? a[i + 8] : a[i]) + got;
            }
            hb = (lane & 2) != 0;
#pragma unroll
            for (int i = 0; i < 4; ++i) {
                float give = hb ? a[i] : a[i + 4];
                float got = __shfl_xor(give, 2, 64);
                a[i] = (hb ? a[i + 4] : a[i]) + got;
            }
            hb = (lane & 4) != 0;
#pragma unroll
            for (int i = 0; i < 2; ++i) {
                float give = hb ? a[i] : a[i + 2];
                float got = __shfl_xor(give, 4, 64);
                a[i] = (hb ? a[i + 2] : a[i]) + got;
            }
            {
                hb = (lane & 8) != 0;
                float give = hb ? a[0] : a[1];
                float got = __shfl_xor(give, 8, 64);
                a[0] = (hb ? a[1] : a[0]) + got;
            }
            a[0] += __shfl_xor(a[0], 16, 64);
            a[0] += __shfl_xor(a[0], 32, 64);
            if (lane < 16) P[(pair * 8 + rr) * 32 + half * 16 + f] = a[0];
        }
        __syncthreads();
        {
            int rloc = t >> 4, j = t & 15;
            int row = base + rloc;
            if (row < rowend)
                m1[(size_t)row * 16 + j] = P[rloc * 32 + j] + P[rloc * 32 + 16 + j];
        }
        __syncthreads();
    }
}

// ---------------------- layer-1 aggregate + bias + ReLU + h@W2, per bucket
// ONE EDGE PER LANE: 4 independent dwordx4 gathers per lane (high MLP);
// LDS acc stride 17 so (17*dloc+j)%32 spreads atomics over all banks.
__global__ __launch_bounds__(512) void agg1(const unsigned int* __restrict__ binned,
        const float* __restrict__ norm, const int* __restrict__ counts,
        const float* __restrict__ dinv, const float* __restrict__ m1,
        const float* __restrict__ b1, const float* __restrict__ W2,
        float* __restrict__ m2) {
    __shared__ float acc[BKT_SIZE * 17];
    __shared__ float sW2[N_HID * N_CLS];
    __shared__ float sb1[N_HID];
    int t = threadIdx.x, b = blockIdx.x;
    for (int i = t; i < BKT_SIZE * 17; i += 512) acc[i] = 0.f;
    if (t < N_HID * N_CLS) sW2[t] = W2[t];
    if (t < N_HID) sb1[t] = b1[t];
    __syncthreads();
    int beg = counts[b * NBLK_BIN];
    int end = (b < NBKT - 1) ? counts[(b + 1) * NBLK_BIN] : N_EDGES;
    for (int e = beg + t; e < end; e += 512) {
        unsigned int v = binned[e];
        float nm = norm[e];
        int s = v & 0x1FFFF;
        int dl = (v >> 17) & (BKT_SIZE - 1);
        const float4* r = (const float4*)&m1[(size_t)s * 16];
        float4 r0 = r[0], r1 = r[1], r2 = r[2], r3 = r[3];
        float* a = &acc[dl * 17];
        atomicAdd(a + 0,  r0.x * nm);
        atomicAdd(a + 1,  r0.y * nm);
        atomicAdd(a + 2,  r0.z * nm);
        atomicAdd(a + 3,  r0.w * nm);
        atomicAdd(a + 4,  r1.x * nm);
        atomicAdd(a + 5,  r1.y * nm);
        atomicAdd(a + 6,  r1.z * nm);
        atomicAdd(a + 7,  r1.w * nm);
        atomicAdd(a + 8,  r2.x * nm);
        atomicAdd(a + 9,  r2.y * nm);
        atomicAdd(a + 10, r2.z * nm);
        atomicAdd(a + 11, r2.w * nm);
        atomicAdd(a + 12, r3.x * nm);
        atomicAdd(a + 13, r3.y * nm);
        atomicAdd(a + 14, r3.z * nm);
        atomicAdd(a + 15, r3.w * nm);
    }
    __syncthreads();
    // h = relu(acc + m1[g]*dinv^2 + b1), in place (stride 17)
    for (int idx = t; idx < BKT_SIZE * 16; idx += 512) {
        int n = idx >> 4, jj = idx & 15;
        int g = b * BKT_SIZE + n;
        if (g < N_NODES) {
            float di = dinv[g];
            float hv = acc[n * 17 + jj] + m1[(size_t)g * 16 + jj] * di * di + sb1[jj];
            acc[n * 17 + jj] = hv > 0.f ? hv : 0.f;
        }
    }
    __syncthreads();
    // m2 = h @ W2 (stride 8, slot 7 zero-padded)
    for (int idx = t; idx < BKT_SIZE * 8; idx += 512) {
        int n = idx >> 3, cc = idx & 7;
        int g = b * BKT_SIZE + n;
        if (g < N_NODES) {
            float sum = 0.f;
            if (cc < N_CLS) {
#pragma unroll
                for (int jj = 0; jj < N_HID; ++jj) sum += acc[n * 17 + jj] * sW2[jj * 7 + cc];
            }
            m2[(size_t)g * 8 + cc] = sum;
        }
    }
}

// ---------------------- layer-2 aggregate + bias + log-softmax, per bucket
// ONE EDGE PER LANE: 2 dwordx4 gathers (m2 stride 8); acc stride 9 for banks.
__global__ __launch_bounds__(512) void agg2(const unsigned int* __restrict__ binned,
        const float* __restrict__ norm, const int* __restrict__ counts,
        const float* __restrict__ dinv, const float* __restrict__ m2,
        const float* __restrict__ b2, float* __restrict__ out) {
    __shared__ float acc[BKT_SIZE * 9];
    int t = threadIdx.x, b = blockIdx.x;
    for (int i = t; i < BKT_SIZE * 9; i += 512) acc[i] = 0.f;
    __syncthreads();
    int beg = counts[b * NBLK_BIN];
    int end = (b < NBKT - 1) ? counts[(b + 1) * NBLK_BIN] : N_EDGES;
    for (int e = beg + t; e < end; e += 512) {
        unsigned int v = binned[e];
        float nm = norm[e];
        int s = v & 0x1FFFF;
        int dl = (v >> 17) & (BKT_SIZE - 1);
        const float4* r = (const float4*)&m2[(size_t)s * 8];
        float4 r0 = r[0], r1 = r[1];
        float* a = &acc[dl * 9];
        atomicAdd(a + 0, r0.x * nm);
        atomicAdd(a + 1, r0.y * nm);
        atomicAdd(a + 2, r0.z * nm);
        atomicAdd(a + 3, r0.w * nm);
        atomicAdd(a + 4, r1.x * nm);
        atomicAdd(a + 5, r1.y * nm);
        atomicAdd(a + 6, r1.z * nm);
    }
    __syncthreads();
    int j = t & 7;
    for (int pass = 0; pass < 2; ++pass) {
        int n = (t >> 3) + pass * 64;
        int g = b * BKT_SIZE + n;
        bool valid = (g < N_NODES) && (j < N_CLS);
        float v = -1e30f;
        if (valid) {
            float di = dinv[g];
            v = acc[n * 9 + j] + m2[(size_t)g * 8 + j] * di * di + b2[j];
        }
        float mx = v;
#pragma unroll
        for (int off = 1; off < 8; off <<= 1) mx = fmaxf(mx, __shfl_xor(mx, off, 8));
        float ex = valid ? expf(v - mx) : 0.f;
        float sum = ex;
#pragma unroll
        for (int off = 1; off < 8; off <<= 1) sum += __shfl_xor(sum, off, 8);
        float ls = mx + logf(sum);
        if (valid) out[(size_t)g * 7 + j] = v - ls;
    }
}

// ----------------------------------------------------------------
extern "C" void kernel_launch(void* const* d_in, const int* in_sizes, int n_in,
                              void* d_out, int out_size, void* d_ws, size_t ws_size,
                              hipStream_t stream) {
    const float* x  = (const float*)d_in[0];
    const int*   ei = (const int*)d_in[1];
    const float* W1 = (const float*)d_in[2];
    const float* b1 = (const float*)d_in[3];
    const float* W2 = (const float*)d_in[4];
    const float* b2 = (const float*)d_in[5];
    float* out = (float*)d_out;
    char*  wsb = (char*)d_ws;   // needs 36.4 MB

    const int* src = ei;               // edge_index[0]
    const int* dst = ei + N_EDGES;     // edge_index[1]

    float*        dinv   = (float*)(wsb) + OFF_DINV;
    int*          counts = (int*  )(wsb) + OFF_COUNTS;
    int*          bsum   = (int*  )(wsb) + OFF_BSUM;
    unsigned int* binned = (unsigned int*)(wsb) + OFF_BINNED;
    float*        norm   = (float*)(wsb) + OFF_NORM;
    float*        m1     = (float*)(wsb) + OFF_M1;
    float*        m2     = (float*)(wsb) + OFF_M2;

    hist     <<<NBLK_BIN, 256, 0, stream>>>(dst, counts);
    scanA    <<<NBLK_SCANA, 256, 0, stream>>>(counts, bsum);
    scanB    <<<1, 1024, 0, stream>>>(bsum);
    scanC    <<<NBLK_SCANA, 256, 0, stream>>>(counts, bsum);
    binpass  <<<NBLK_BIN, 256, 0, stream>>>(src, dst, counts, binned);
    bucketdeg<<<NBKT, 256, 0, stream>>>(binned, counts, dinv);
    normfill <<<NBKT, 256, 0, stream>>>(binned, counts, dinv, norm);
    gemm1    <<<G1_BLOCKS, 256, 0, stream>>>(x, W1, m1);
    agg1     <<<NBKT, 512, 0, stream>>>(binned, norm, counts, dinv, m1, b1, W2, m2);
    agg2     <<<NBKT, 512, 0, stream>>>(binned, norm, counts, dinv, m2, b2, out);
}

// Round 5
// 952.225 us; speedup vs baseline: 1.0290x; 1.0136x over previous
//
#include <hip/hip_runtime.h>
#include <math.h>

#define N_NODES 100000
#define N_EDGES 3200000
#define N_FEAT  500
#define NF4     125      // N_FEAT / 4
#define N_HID   16
#define N_CLS   7

#define BKT_SHIFT 7
#define BKT_SIZE  128
#define NBKT      782            // ceil(100000/128)
#define NBLK_BIN  256            // edge-chunk blocks for hist/binpass
#define EDGES_PER_BLK 12500      // 256 * 12500 = 3.2M exactly
#define COUNTS_LEN (NBKT * NBLK_BIN)   // 200192
#define NBLK_SCANA (COUNTS_LEN / 256)  // 782 exactly

// ---------------- workspace layout (dword offsets) --------------------------
#define OFF_DINV   0            // 100000 f
#define OFF_COUNTS 100000       // 200192 i
#define OFF_BSUM   300192       // 1024 i
#define OFF_BINNED 301216       // 3200000 u32 (src | dst_local<<17)
#define OFF_M1S    3501216      // 1600000 ushort bf16 (m1*dinv), 32 B/row
#define OFF_M2S    4301216      // 800000 ushort bf16 (m2*dinv), 16 B/row (pad 8th)
// total 4,701,216 dwords = 18.8 MB

// ------------------------------------------------------------- bf16 helpers
__device__ inline unsigned short f2bf(float f) {
    unsigned int u = __float_as_uint(f);
    return (unsigned short)((u + 0x7FFF + ((u >> 16) & 1)) >> 16);
}
__device__ inline float bf2f(unsigned short h) {
    return __uint_as_float((unsigned int)h << 16);
}
// dword holds features {2k (lo), 2k+1 (hi)}
__device__ inline void add2(float* a, unsigned int u) {
    atomicAdd(a + 0, __uint_as_float(u << 16));
    atomicAdd(a + 1, __uint_as_float(u & 0xFFFF0000u));
}

// ------------------------------------------------------------- pass 1: hist
__global__ void hist(const int* __restrict__ dst, int* __restrict__ counts) {
    __shared__ int cnt[NBKT];
    int t = threadIdx.x, b = blockIdx.x;
    for (int i = t; i < NBKT; i += 256) cnt[i] = 0;
    __syncthreads();
    int e0 = b * EDGES_PER_BLK;
    for (int e = e0 + t; e < e0 + EDGES_PER_BLK; e += 256)
        atomicAdd(&cnt[dst[e] >> BKT_SHIFT], 1);
    __syncthreads();
    for (int i = t; i < NBKT; i += 256)
        counts[i * NBLK_BIN + b] = cnt[i];
}

// ------------------------------------------------------------- scan chain
__global__ void scanA(int* __restrict__ counts, int* __restrict__ bsum) {
    __shared__ int s[256];
    int t = threadIdx.x;
    int i = blockIdx.x * 256 + t;
    int v = counts[i];
    s[t] = v;
    __syncthreads();
    for (int off = 1; off < 256; off <<= 1) {
        int a = (t >= off) ? s[t - off] : 0;
        __syncthreads();
        s[t] += a;
        __syncthreads();
    }
    counts[i] = s[t] - v;
    if (t == 255) bsum[blockIdx.x] = s[255];
}

__global__ void scanB(int* __restrict__ bsum) {
    __shared__ int s[1024];
    int t = threadIdx.x;
    int v = (t < NBLK_SCANA) ? bsum[t] : 0;
    s[t] = v;
    __syncthreads();
    for (int off = 1; off < 1024; off <<= 1) {
        int a = (t >= off) ? s[t - off] : 0;
        __syncthreads();
        s[t] += a;
        __syncthreads();
    }
    if (t < NBLK_SCANA) bsum[t] = s[t] - v;
}

__global__ void scanC(int* __restrict__ counts, const int* __restrict__ bsum) {
    int i = blockIdx.x * 256 + threadIdx.x;
    counts[i] += bsum[i >> 8];
}

// ------------------------------------------------------------- pass 2: bin
__global__ void binpass(const int* __restrict__ src, const int* __restrict__ dst,
                        const int* __restrict__ counts, unsigned int* __restrict__ binned) {
    __shared__ int cur[NBKT];
    int t = threadIdx.x, b = blockIdx.x;
    for (int i = t; i < NBKT; i += 256) cur[i] = counts[i * NBLK_BIN + b];
    __syncthreads();
    int e0 = b * EDGES_PER_BLK;
    for (int e = e0 + t; e < e0 + EDGES_PER_BLK; e += 256) {
        int d = dst[e];
        int pos = atomicAdd(&cur[d >> BKT_SHIFT], 1);
        binned[pos] = (unsigned int)src[e] | ((unsigned int)(d & (BKT_SIZE - 1)) << 17);
    }
}

// ---------------------------------------------- per-bucket degrees -> dinv
__global__ void bucketdeg(const unsigned int* __restrict__ binned,
                          const int* __restrict__ counts, float* __restrict__ dinv) {
    __shared__ int cnt[BKT_SIZE];
    int t = threadIdx.x, b = blockIdx.x;
    if (t < BKT_SIZE) cnt[t] = 0;
    __syncthreads();
    int beg = counts[b * NBLK_BIN];
    int end = (b < NBKT - 1) ? counts[(b + 1) * NBLK_BIN] : N_EDGES;
    for (int e = beg + t; e < end; e += 256)
        atomicAdd(&cnt[(binned[e] >> 17) & (BKT_SIZE - 1)], 1);
    __syncthreads();
    if (t < BKT_SIZE) {
        int g = b * BKT_SIZE + t;
        if (g < N_NODES) dinv[g] = rsqrtf((float)cnt[t] + 1.0f);  // +1 self loop
    }
}

// ------------------------------------------- m1s = bf16((x @ W1) * dinv)
#define G1_BLOCKS 512
#define G1_ROWS_PER_BLOCK 196   // 512*196 >= 100000

__global__ __launch_bounds__(256) void gemm1(const float* __restrict__ x,
                                             const float* __restrict__ W1,
                                             const float* __restrict__ dinv,
                                             unsigned short* __restrict__ m1s) {
    __shared__ float P[16 * 32];
    const int t = threadIdx.x;
    const int lane = t & 63;
    const int w = t >> 6;
    const int half = w & 1;
    const int pair = w >> 1;
    const int c = half * 64 + lane;

    float4 wr[4][4];
#pragma unroll
    for (int r = 0; r < 4; ++r)
#pragma unroll
        for (int q = 0; q < 4; ++q)
            wr[r][q] = (c < NF4) ? *(const float4*)&W1[(4 * c + r) * 16 + 4 * q]
                                 : make_float4(0.f, 0.f, 0.f, 0.f);
    const int f = ((lane & 1) << 3) | ((lane & 2) << 1) | ((lane & 4) >> 1) | ((lane & 8) >> 3);

    const float4* x4 = (const float4*)x;
    int row0 = blockIdx.x * G1_ROWS_PER_BLOCK;
    int rowend = row0 + G1_ROWS_PER_BLOCK;
    if (rowend > N_NODES) rowend = N_NODES;

    for (int base = row0; base < rowend; base += 16) {
        for (int rr = 0; rr < 8; ++rr) {
            int row = base + pair * 8 + rr;
            float4 xv = make_float4(0.f, 0.f, 0.f, 0.f);
            if (row < rowend && c < NF4) xv = x4[(size_t)row * NF4 + c];
            float a[16];
#pragma unroll
            for (int q = 0; q < 4; ++q) {
                a[4*q+0] = xv.x*wr[0][q].x + xv.y*wr[1][q].x + xv.z*wr[2][q].x + xv.w*wr[3][q].x;
                a[4*q+1] = xv.x*wr[0][q].y + xv.y*wr[1][q].y + xv.z*wr[2][q].y + xv.w*wr[3][q].y;
                a[4*q+2] = xv.x*wr[0][q].z + xv.y*wr[1][q].z + xv.z*wr[2][q].z + xv.w*wr[3][q].z;
                a[4*q+3] = xv.x*wr[0][q].w + xv.y*wr[1][q].w + xv.z*wr[2][q].w + xv.w*wr[3][q].w;
            }
            bool hb = (lane & 1) != 0;
#pragma unroll
            for (int i = 0; i < 8; ++i) {
                float give = hb ? a[i] : a[i + 8];
                float got = __shfl_xor(give, 1, 64);
                a[i] = (hb ? a[i + 8] : a[i]) + got;
            }
            hb = (lane & 2) != 0;
#pragma unroll
            for (int i = 0; i < 4; ++i) {
                float give = hb ? a[i] : a[i + 4];
                float got = __shfl_xor(give, 2, 64);
                a[i] = (hb ? a[i + 4] : a[i]) + got;
            }
            hb = (lane & 4) != 0;
#pragma unroll
            for (int i = 0; i < 2; ++i) {
                float give = hb ? a[i] : a[i + 2];
                float got = __shfl_xor(give, 4, 64);
                a[i] = (hb ? a[i + 2] : a[i]) + got;
            }
            {
                hb = (lane & 8) != 0;
                float give = hb ? a[0] : a[1];
                float got = __shfl_xor(give, 8, 64);
                a[0] = (hb ? a[1] : a[0]) + got;
            }
            a[0] += __shfl_xor(a[0], 16, 64);
            a[0] += __shfl_xor(a[0], 32, 64);
            if (lane < 16) P[(pair * 8 + rr) * 32 + half * 16 + f] = a[0];
        }
        __syncthreads();
        {
            int rloc = t >> 4, j = t & 15;
            int row = base + rloc;
            if (row < rowend) {
                float val = P[rloc * 32 + j] + P[rloc * 32 + 16 + j];
                m1s[(size_t)row * 16 + j] = f2bf(val * dinv[row]);
            }
        }
        __syncthreads();
    }
}

// ---------------------- layer-1 aggregate + bias + ReLU + h@W2, per bucket
// 2 lanes per edge, one dwordx4 each (coalesces to ~32B/edge L2 requests).
// m1s (3.2 MB bf16) is per-XCD-L2 resident. acc stride 17 spreads LDS banks.
__global__ __launch_bounds__(512) void agg1(const unsigned int* __restrict__ binned,
        const int* __restrict__ counts, const float* __restrict__ dinv,
        const unsigned short* __restrict__ m1s, const float* __restrict__ b1,
        const float* __restrict__ W2, unsigned short* __restrict__ m2s) {
    __shared__ float acc[BKT_SIZE * 17];
    __shared__ float sW2[N_HID * N_CLS];
    __shared__ float sb1[N_HID];
    int t = threadIdx.x, b = blockIdx.x;
    for (int i = t; i < BKT_SIZE * 17; i += 512) acc[i] = 0.f;
    if (t < N_HID * N_CLS) sW2[t] = W2[t];
    if (t < N_HID) sb1[t] = b1[t];
    __syncthreads();
    int beg = counts[b * NBLK_BIN];
    int end = (b < NBKT - 1) ? counts[(b + 1) * NBLK_BIN] : N_EDGES;
    int q = t & 1, eo = t >> 1;    // 256 edges per iteration, unroll x2
    for (int e0 = beg + eo; e0 < end; e0 += 512) {
        int e1 = e0 + 256;
        bool has1 = e1 < end;
        unsigned int v0 = binned[e0];
        unsigned int v1 = has1 ? binned[e1] : 0u;
        uint4 w0 = *(const uint4*)&m1s[(size_t)(v0 & 0x1FFFF) * 16 + q * 8];
        uint4 w1 = make_uint4(0, 0, 0, 0);
        if (has1) w1 = *(const uint4*)&m1s[(size_t)(v1 & 0x1FFFF) * 16 + q * 8];
        {
            float* a = &acc[((v0 >> 17) & (BKT_SIZE - 1)) * 17 + q * 8];
            add2(a + 0, w0.x); add2(a + 2, w0.y);
            add2(a + 4, w0.z); add2(a + 6, w0.w);
        }
        if (has1) {
            float* a = &acc[((v1 >> 17) & (BKT_SIZE - 1)) * 17 + q * 8];
            add2(a + 0, w1.x); add2(a + 2, w1.y);
            add2(a + 4, w1.z); add2(a + 6, w1.w);
        }
    }
    __syncthreads();
    // h = relu(dinv_g * (acc + m1s_g) + b1), in place (stride 17)
    for (int idx = t; idx < BKT_SIZE * 16; idx += 512) {
        int n = idx >> 4, jj = idx & 15;
        int g = b * BKT_SIZE + n;
        if (g < N_NODES) {
            float di = dinv[g];
            float hv = di * (acc[n * 17 + jj] + bf2f(m1s[(size_t)g * 16 + jj])) + sb1[jj];
            acc[n * 17 + jj] = hv > 0.f ? hv : 0.f;
        }
    }
    __syncthreads();
    // m2s = bf16(dinv_g * (h @ W2)), stride 8, slot 7 = 0 pad
    for (int idx = t; idx < BKT_SIZE * 8; idx += 512) {
        int n = idx >> 3, cc = idx & 7;
        int g = b * BKT_SIZE + n;
        if (g < N_NODES) {
            float sum = 0.f;
            if (cc < N_CLS) {
#pragma unroll
                for (int jj = 0; jj < N_HID; ++jj) sum += acc[n * 17 + jj] * sW2[jj * 7 + cc];
                sum *= dinv[g];
            }
            m2s[(size_t)g * 8 + cc] = f2bf(sum);
        }
    }
}

// ---------------------- layer-2 aggregate + bias + log-softmax, per bucket
// 1 lane per edge, one dwordx4 (16 B row). acc stride 9 spreads banks.
__global__ __launch_bounds__(512) void agg2(const unsigned int* __restrict__ binned,
        const int* __restrict__ counts, const float* __restrict__ dinv,
        const unsigned short* __restrict__ m2s, const float* __restrict__ b2,
        float* __restrict__ out) {
    __shared__ float acc[BKT_SIZE * 9];
    int t = threadIdx.x, b = blockIdx.x;
    for (int i = t; i < BKT_SIZE * 9; i += 512) acc[i] = 0.f;
    __syncthreads();
    int beg = counts[b * NBLK_BIN];
    int end = (b < NBKT - 1) ? counts[(b + 1) * NBLK_BIN] : N_EDGES;
    for (int e0 = beg + t; e0 < end; e0 += 1024) {
        int e1 = e0 + 512;
        bool has1 = e1 < end;
        unsigned int v0 = binned[e0];
        unsigned int v1 = has1 ? binned[e1] : 0u;
        uint4 w0 = *(const uint4*)&m2s[(size_t)(v0 & 0x1FFFF) * 8];
        uint4 w1 = make_uint4(0, 0, 0, 0);
        if (has1) w1 = *(const uint4*)&m2s[(size_t)(v1 & 0x1FFFF) * 8];
        {
            float* a = &acc[((v0 >> 17) & (BKT_SIZE - 1)) * 9];
            add2(a + 0, w0.x); add2(a + 2, w0.y); add2(a + 4, w0.z);
            atomicAdd(a + 6, __uint_as_float(w0.w << 16));   // class 6 only
        }
        if (has1) {
            float* a = &acc[((v1 >> 17) & (BKT_SIZE - 1)) * 9];
            add2(a + 0, w1.x); add2(a + 2, w1.y); add2(a + 4, w1.z);
            atomicAdd(a + 6, __uint_as_float(w1.w << 16));
        }
    }
    __syncthreads();
    int j = t & 7;
    for (int pass = 0; pass < 2; ++pass) {
        int n = (t >> 3) + pass * 64;
        int g = b * BKT_SIZE + n;
        bool valid = (g < N_NODES) && (j < N_CLS);
        float v = -1e30f;
        if (valid) {
            float di = dinv[g];
            v = di * (acc[n * 9 + j] + bf2f(m2s[(size_t)g * 8 + j])) + b2[j];
        }
        float mx = v;
#pragma unroll
        for (int off = 1; off < 8; off <<= 1) mx = fmaxf(mx, __shfl_xor(mx, off, 8));
        float ex = valid ? expf(v - mx) : 0.f;
        float sum = ex;
#pragma unroll
        for (int off = 1; off < 8; off <<= 1) sum += __shfl_xor(sum, off, 8);
        float ls = mx + logf(sum);
        if (valid) out[(size_t)g * 7 + j] = v - ls;
    }
}

// ----------------------------------------------------------------
extern "C" void kernel_launch(void* const* d_in, const int* in_sizes, int n_in,
                              void* d_out, int out_size, void* d_ws, size_t ws_size,
                              hipStream_t stream) {
    const float* x  = (const float*)d_in[0];
    const int*   ei = (const int*)d_in[1];
    const float* W1 = (const float*)d_in[2];
    const float* b1 = (const float*)d_in[3];
    const float* W2 = (const float*)d_in[4];
    const float* b2 = (const float*)d_in[5];
    float* out = (float*)d_out;
    char*  wsb = (char*)d_ws;   // needs 18.8 MB

    const int* src = ei;               // edge_index[0]
    const int* dst = ei + N_EDGES;     // edge_index[1]

    float*          dinv   = (float*)wsb + OFF_DINV;
    int*            counts = (int*)wsb + OFF_COUNTS;
    int*            bsum   = (int*)wsb + OFF_BSUM;
    unsigned int*   binned = (unsigned int*)wsb + OFF_BINNED;
    unsigned short* m1s    = (unsigned short*)(wsb + (size_t)OFF_M1S * 4);
    unsigned short* m2s    = (unsigned short*)(wsb + (size_t)OFF_M2S * 4);

    hist     <<<NBLK_BIN, 256, 0, stream>>>(dst, counts);
    scanA    <<<NBLK_SCANA, 256, 0, stream>>>(counts, bsum);
    scanB    <<<1, 1024, 0, stream>>>(bsum);
    scanC    <<<NBLK_SCANA, 256, 0, stream>>>(counts, bsum);
    binpass  <<<NBLK_BIN, 256, 0, stream>>>(src, dst, counts, binned);
    bucketdeg<<<NBKT, 256, 0, stream>>>(binned, counts, dinv);
    gemm1    <<<G1_BLOCKS, 256, 0, stream>>>(x, W1, dinv, m1s);
    agg1     <<<NBKT, 512, 0, stream>>>(binned, counts, dinv, m1s, b1, W2, m2s);
    agg2     <<<NBKT, 512, 0, stream>>>(binned, counts, dinv, m2s, b2, out);
}

// Round 6
// 545.744 us; speedup vs baseline: 1.7954x; 1.7448x over previous
//
#include <hip/hip_runtime.h>
#include <math.h>

#define N_NODES 100000
#define N_EDGES 3200000
#define N_FEAT  500
#define NF4     125      // N_FEAT / 4
#define N_HID   16
#define N_CLS   7

#define BKT_SHIFT 7
#define BKT_SIZE  128
#define NBKT      782            // ceil(100000/128)
#define NBLK_BIN  256            // edge-chunk blocks for hist/binpass
#define EDGES_PER_BLK 12500      // 256 * 12500 = 3.2M exactly
#define COUNTS_LEN (NBKT * NBLK_BIN)   // 200192
#define NBLK_SCANA (COUNTS_LEN / 256)  // 782 exactly
#define SBUF_CAP  5632           // max edges/bucket (mean 4092, sd 64 -> 24 sd)

// ---------------- workspace layout (dword offsets) --------------------------
#define OFF_DINV   0            // 100000 f
#define OFF_COUNTS 100000       // 200192 i
#define OFF_BSUM   300192       // 1024 i
#define OFF_ROWP   301216       // 100001 i (+3 pad)
#define OFF_BINNED 401220       // 3200000 u32 (src | dst_local<<17)
#define OFF_SORTED 3601220      // 3200000 u32 (src, grouped per dst node)
#define OFF_M1S    6801220      // 1600000 ushort bf16 (m1*dinv), 32 B/row
#define OFF_M2S    7601220      // 800000 ushort bf16 (m2*dinv), 16 B/row (pad 8th)
// total 8,001,220 dwords = 32.0 MB

// ------------------------------------------------------------- bf16 helpers
__device__ inline unsigned short f2bf(float f) {
    unsigned int u = __float_as_uint(f);
    return (unsigned short)((u + 0x7FFF + ((u >> 16) & 1)) >> 16);
}
__device__ inline float bf2f(unsigned short h) {
    return __uint_as_float((unsigned int)h << 16);
}

// ------------------------------------------------------------- pass 1: hist
__global__ void hist(const int* __restrict__ dst, int* __restrict__ counts) {
    __shared__ int cnt[NBKT];
    int t = threadIdx.x, b = blockIdx.x;
    for (int i = t; i < NBKT; i += 256) cnt[i] = 0;
    __syncthreads();
    int e0 = b * EDGES_PER_BLK;
    for (int e = e0 + t; e < e0 + EDGES_PER_BLK; e += 256)
        atomicAdd(&cnt[dst[e] >> BKT_SHIFT], 1);
    __syncthreads();
    for (int i = t; i < NBKT; i += 256)
        counts[i * NBLK_BIN + b] = cnt[i];
}

// ------------------------------------------------------------- scan chain
__global__ void scanA(int* __restrict__ counts, int* __restrict__ bsum) {
    __shared__ int s[256];
    int t = threadIdx.x;
    int i = blockIdx.x * 256 + t;
    int v = counts[i];
    s[t] = v;
    __syncthreads();
    for (int off = 1; off < 256; off <<= 1) {
        int a = (t >= off) ? s[t - off] : 0;
        __syncthreads();
        s[t] += a;
        __syncthreads();
    }
    counts[i] = s[t] - v;
    if (t == 255) bsum[blockIdx.x] = s[255];
}

__global__ void scanB(int* __restrict__ bsum) {
    __shared__ int s[1024];
    int t = threadIdx.x;
    int v = (t < NBLK_SCANA) ? bsum[t] : 0;
    s[t] = v;
    __syncthreads();
    for (int off = 1; off < 1024; off <<= 1) {
        int a = (t >= off) ? s[t - off] : 0;
        __syncthreads();
        s[t] += a;
        __syncthreads();
    }
    if (t < NBLK_SCANA) bsum[t] = s[t] - v;
}

__global__ void scanC(int* __restrict__ counts, const int* __restrict__ bsum) {
    int i = blockIdx.x * 256 + threadIdx.x;
    counts[i] += bsum[i >> 8];
}

// ------------------------------------------------------------- pass 2: bin
__global__ void binpass(const int* __restrict__ src, const int* __restrict__ dst,
                        const int* __restrict__ counts, unsigned int* __restrict__ binned) {
    __shared__ int cur[NBKT];
    int t = threadIdx.x, b = blockIdx.x;
    for (int i = t; i < NBKT; i += 256) cur[i] = counts[i * NBLK_BIN + b];
    __syncthreads();
    int e0 = b * EDGES_PER_BLK;
    for (int e = e0 + t; e < e0 + EDGES_PER_BLK; e += 256) {
        int d = dst[e];
        int pos = atomicAdd(&cur[d >> BKT_SHIFT], 1);
        binned[pos] = (unsigned int)src[e] | ((unsigned int)(d & (BKT_SIZE - 1)) << 17);
    }
}

// ---------------------- pass 3: per-bucket sort by node + rowptr + dinv
__global__ __launch_bounds__(512) void sortpass(const unsigned int* __restrict__ binned,
        const int* __restrict__ counts, unsigned int* __restrict__ sorted,
        int* __restrict__ rowptr, float* __restrict__ dinv) {
    __shared__ int cnt[BKT_SIZE];
    __shared__ int sc[BKT_SIZE];
    __shared__ int cur[BKT_SIZE];
    __shared__ unsigned int sbuf[SBUF_CAP];
    int t = threadIdx.x, b = blockIdx.x;
    int beg = counts[b * NBLK_BIN];
    int end = (b < NBKT - 1) ? counts[(b + 1) * NBLK_BIN] : N_EDGES;
    if (t < BKT_SIZE) cnt[t] = 0;
    __syncthreads();
    for (int e = beg + t; e < end; e += 512)
        atomicAdd(&cnt[(binned[e] >> 17) & (BKT_SIZE - 1)], 1);
    __syncthreads();
    int v = (t < BKT_SIZE) ? cnt[t] : 0;
    if (t < BKT_SIZE) sc[t] = v;
    __syncthreads();
    for (int off = 1; off < BKT_SIZE; off <<= 1) {
        int a = (t < BKT_SIZE && t >= off) ? sc[t - off] : 0;
        __syncthreads();
        if (t < BKT_SIZE) sc[t] += a;
        __syncthreads();
    }
    if (t < BKT_SIZE) {
        cur[t] = sc[t] - v;                    // exclusive, bucket-local
        int g = b * BKT_SIZE + t;
        if (g < N_NODES) {
            rowptr[g] = beg + sc[t] - v;
            dinv[g] = rsqrtf((float)v + 1.0f);  // +1 self loop
        }
    }
    if (b == 0 && t == 0) rowptr[N_NODES] = N_EDGES;
    __syncthreads();
    for (int e = beg + t; e < end; e += 512) {
        unsigned int u = binned[e];
        int pos = atomicAdd(&cur[(u >> 17) & (BKT_SIZE - 1)], 1);
        if (pos < SBUF_CAP) sbuf[pos] = u & 0x1FFFF;
    }
    __syncthreads();
    int n = end - beg;
    for (int i = t; i < n; i += 512) sorted[beg + i] = sbuf[i];
}

// ------------------------------------------- m1s = bf16((x @ W1) * dinv)
#define G1_BLOCKS 512
#define G1_ROWS_PER_BLOCK 196   // 512*196 >= 100000

__global__ __launch_bounds__(256) void gemm1(const float* __restrict__ x,
                                             const float* __restrict__ W1,
                                             const float* __restrict__ dinv,
                                             unsigned short* __restrict__ m1s) {
    __shared__ float P[16 * 32];
    const int t = threadIdx.x;
    const int lane = t & 63;
    const int w = t >> 6;
    const int half = w & 1;
    const int pair = w >> 1;
    const int c = half * 64 + lane;

    float4 wr[4][4];
#pragma unroll
    for (int r = 0; r < 4; ++r)
#pragma unroll
        for (int q = 0; q < 4; ++q)
            wr[r][q] = (c < NF4) ? *(const float4*)&W1[(4 * c + r) * 16 + 4 * q]
                                 : make_float4(0.f, 0.f, 0.f, 0.f);
    const int f = ((lane & 1) << 3) | ((lane & 2) << 1) | ((lane & 4) >> 1) | ((lane & 8) >> 3);

    const float4* x4 = (const float4*)x;
    int row0 = blockIdx.x * G1_ROWS_PER_BLOCK;
    int rowend = row0 + G1_ROWS_PER_BLOCK;
    if (rowend > N_NODES) rowend = N_NODES;

    for (int base = row0; base < rowend; base += 16) {
        for (int rr = 0; rr < 8; ++rr) {
            int row = base + pair * 8 + rr;
            float4 xv = make_float4(0.f, 0.f, 0.f, 0.f);
            if (row < rowend && c < NF4) xv = x4[(size_t)row * NF4 + c];
            float a[16];
#pragma unroll
            for (int q = 0; q < 4; ++q) {
                a[4*q+0] = xv.x*wr[0][q].x + xv.y*wr[1][q].x + xv.z*wr[2][q].x + xv.w*wr[3][q].x;
                a[4*q+1] = xv.x*wr[0][q].y + xv.y*wr[1][q].y + xv.z*wr[2][q].y + xv.w*wr[3][q].y;
                a[4*q+2] = xv.x*wr[0][q].z + xv.y*wr[1][q].z + xv.z*wr[2][q].z + xv.w*wr[3][q].z;
                a[4*q+3] = xv.x*wr[0][q].w + xv.y*wr[1][q].w + xv.z*wr[2][q].w + xv.w*wr[3][q].w;
            }
            bool hb = (lane & 1) != 0;
#pragma unroll
            for (int i = 0; i < 8; ++i) {
                float give = hb ? a[i] : a[i + 8];
                float got = __shfl_xor(give, 1, 64);
                a[i] = (hb ? a[i + 8] : a[i]) + got;
            }
            hb = (lane & 2) != 0;
#pragma unroll
            for (int i = 0; i < 4; ++i) {
                float give = hb ? a[i] : a[i + 4];
                float got = __shfl_xor(give, 2, 64);
                a[i] = (hb ? a[i + 4] : a[i]) + got;
            }
            hb = (lane & 4) != 0;
#pragma unroll
            for (int i = 0; i < 2; ++i) {
                float give = hb ? a[i] : a[i + 2];
                float got = __shfl_xor(give, 4, 64);
                a[i] = (hb ? a[i + 2] : a[i]) + got;
            }
            {
                hb = (lane & 8) != 0;
                float give = hb ? a[0] : a[1];
                float got = __shfl_xor(give, 8, 64);
                a[0] = (hb ? a[1] : a[0]) + got;
            }
            a[0] += __shfl_xor(a[0], 16, 64);
            a[0] += __shfl_xor(a[0], 32, 64);
            if (lane < 16) P[(pair * 8 + rr) * 32 + half * 16 + f] = a[0];
        }
        __syncthreads();
        {
            int rloc = t >> 4, j = t & 15;
            int row = base + rloc;
            if (row < rowend) {
                float val = P[rloc * 32 + j] + P[rloc * 32 + 16 + j];
                m1s[(size_t)row * 16 + j] = f2bf(val * dinv[row]);
            }
        }
        __syncthreads();
    }
}

// -------- layer-1 aggregate (register owner-computes) + bias + ReLU + h@W2
// 4 lanes per node; lane q owns features 4q..4q+3; per edge one uint2 (8B);
// the 4 lanes' loads form one 32B row segment. NO atomics.
__global__ __launch_bounds__(512) void agg1(const unsigned int* __restrict__ sorted,
        const int* __restrict__ rowptr, const float* __restrict__ dinv,
        const unsigned short* __restrict__ m1s, const float* __restrict__ b1,
        const float* __restrict__ W2, unsigned short* __restrict__ m2s) {
    __shared__ float acc[BKT_SIZE * 17];
    __shared__ float sW2[N_HID * N_CLS];
    __shared__ float sb1[N_HID];
    int t = threadIdx.x, b = blockIdx.x;
    if (t < N_HID * N_CLS) sW2[t] = W2[t];
    if (t < N_HID) sb1[t] = b1[t];
    int n = t >> 2, q = t & 3;
    int g = b * BKT_SIZE + n;
    float a0 = 0.f, a1 = 0.f, a2 = 0.f, a3 = 0.f;
    if (g < N_NODES) {
        int beg = rowptr[g], end = rowptr[g + 1];
        int p = beg;
        for (; p + 1 < end; p += 2) {
            unsigned int s0 = sorted[p], s1 = sorted[p + 1];
            uint2 w0 = *(const uint2*)&m1s[(size_t)s0 * 16 + q * 4];
            uint2 w1 = *(const uint2*)&m1s[(size_t)s1 * 16 + q * 4];
            a0 += __uint_as_float(w0.x << 16);
            a1 += __uint_as_float(w0.x & 0xFFFF0000u);
            a2 += __uint_as_float(w0.y << 16);
            a3 += __uint_as_float(w0.y & 0xFFFF0000u);
            a0 += __uint_as_float(w1.x << 16);
            a1 += __uint_as_float(w1.x & 0xFFFF0000u);
            a2 += __uint_as_float(w1.y << 16);
            a3 += __uint_as_float(w1.y & 0xFFFF0000u);
        }
        if (p < end) {
            unsigned int s0 = sorted[p];
            uint2 w0 = *(const uint2*)&m1s[(size_t)s0 * 16 + q * 4];
            a0 += __uint_as_float(w0.x << 16);
            a1 += __uint_as_float(w0.x & 0xFFFF0000u);
            a2 += __uint_as_float(w0.y << 16);
            a3 += __uint_as_float(w0.y & 0xFFFF0000u);
        }
    }
    float* ap = &acc[n * 17 + q * 4];
    ap[0] = a0; ap[1] = a1; ap[2] = a2; ap[3] = a3;
    __syncthreads();
    // h = relu(dinv_g * (acc + m1s_g) + b1), in place (stride 17)
    for (int idx = t; idx < BKT_SIZE * 16; idx += 512) {
        int nn = idx >> 4, jj = idx & 15;
        int gg = b * BKT_SIZE + nn;
        if (gg < N_NODES) {
            float di = dinv[gg];
            float hv = di * (acc[nn * 17 + jj] + bf2f(m1s[(size_t)gg * 16 + jj])) + sb1[jj];
            acc[nn * 17 + jj] = hv > 0.f ? hv : 0.f;
        }
    }
    __syncthreads();
    // m2s = bf16(dinv_g * (h @ W2)), stride 8, slot 7 = 0 pad
    for (int idx = t; idx < BKT_SIZE * 8; idx += 512) {
        int nn = idx >> 3, cc = idx & 7;
        int gg = b * BKT_SIZE + nn;
        if (gg < N_NODES) {
            float sum = 0.f;
            if (cc < N_CLS) {
#pragma unroll
                for (int jj = 0; jj < N_HID; ++jj) sum += acc[nn * 17 + jj] * sW2[jj * 7 + cc];
                sum *= dinv[gg];
            }
            m2s[(size_t)gg * 8 + cc] = f2bf(sum);
        }
    }
}

// -------- layer-2 aggregate (register owner-computes) + bias + log-softmax
// 2 lanes per node; lane q owns slots 4q..4q+3 (slot 7 = pad). NO atomics.
__global__ __launch_bounds__(256) void agg2(const unsigned int* __restrict__ sorted,
        const int* __restrict__ rowptr, const float* __restrict__ dinv,
        const unsigned short* __restrict__ m2s, const float* __restrict__ b2,
        float* __restrict__ out) {
    __shared__ float acc[BKT_SIZE * 9];
    int t = threadIdx.x, b = blockIdx.x;
    int n = t >> 1, q = t & 1;
    int g = b * BKT_SIZE + n;
    float a0 = 0.f, a1 = 0.f, a2 = 0.f, a3 = 0.f;
    if (g < N_NODES) {
        int beg = rowptr[g], end = rowptr[g + 1];
        int p = beg;
        for (; p + 1 < end; p += 2) {
            unsigned int s0 = sorted[p], s1 = sorted[p + 1];
            uint2 w0 = *(const uint2*)&m2s[(size_t)s0 * 8 + q * 4];
            uint2 w1 = *(const uint2*)&m2s[(size_t)s1 * 8 + q * 4];
            a0 += __uint_as_float(w0.x << 16);
            a1 += __uint_as_float(w0.x & 0xFFFF0000u);
            a2 += __uint_as_float(w0.y << 16);
            a3 += __uint_as_float(w0.y & 0xFFFF0000u);
            a0 += __uint_as_float(w1.x << 16);
            a1 += __uint_as_float(w1.x & 0xFFFF0000u);
            a2 += __uint_as_float(w1.y << 16);
            a3 += __uint_as_float(w1.y & 0xFFFF0000u);
        }
        if (p < end) {
            unsigned int s0 = sorted[p];
            uint2 w0 = *(const uint2*)&m2s[(size_t)s0 * 8 + q * 4];
            a0 += __uint_as_float(w0.x << 16);
            a1 += __uint_as_float(w0.x & 0xFFFF0000u);
            a2 += __uint_as_float(w0.y << 16);
            a3 += __uint_as_float(w0.y & 0xFFFF0000u);
        }
    }
    float* ap = &acc[n * 9 + q * 4];
    ap[0] = a0; ap[1] = a1; ap[2] = a2; ap[3] = a3;
    __syncthreads();
    int j = t & 7;
    for (int pass = 0; pass < 4; ++pass) {
        int nn = (t >> 3) + pass * 32;
        int gg = b * BKT_SIZE + nn;
        bool valid = (gg < N_NODES) && (j < N_CLS);
        float v = -1e30f;
        if (valid) {
            float di = dinv[gg];
            v = di * (acc[nn * 9 + j] + bf2f(m2s[(size_t)gg * 8 + j])) + b2[j];
        }
        float mx = v;
#pragma unroll
        for (int off = 1; off < 8; off <<= 1) mx = fmaxf(mx, __shfl_xor(mx, off, 8));
        float ex = valid ? expf(v - mx) : 0.f;
        float sum = ex;
#pragma unroll
        for (int off = 1; off < 8; off <<= 1) sum += __shfl_xor(sum, off, 8);
        float ls = mx + logf(sum);
        if (valid) out[(size_t)gg * 7 + j] = v - ls;
    }
}

// ----------------------------------------------------------------
extern "C" void kernel_launch(void* const* d_in, const int* in_sizes, int n_in,
                              void* d_out, int out_size, void* d_ws, size_t ws_size,
                              hipStream_t stream) {
    const float* x  = (const float*)d_in[0];
    const int*   ei = (const int*)d_in[1];
    const float* W1 = (const float*)d_in[2];
    const float* b1 = (const float*)d_in[3];
    const float* W2 = (const float*)d_in[4];
    const float* b2 = (const float*)d_in[5];
    float* out = (float*)d_out;
    char*  wsb = (char*)d_ws;   // needs 32.0 MB

    const int* src = ei;               // edge_index[0]
    const int* dst = ei + N_EDGES;     // edge_index[1]

    float*          dinv   = (float*)wsb + OFF_DINV;
    int*            counts = (int*)wsb + OFF_COUNTS;
    int*            bsum   = (int*)wsb + OFF_BSUM;
    int*            rowptr = (int*)wsb + OFF_ROWP;
    unsigned int*   binned = (unsigned int*)wsb + OFF_BINNED;
    unsigned int*   sorted = (unsigned int*)wsb + OFF_SORTED;
    unsigned short* m1s    = (unsigned short*)(wsb + (size_t)OFF_M1S * 4);
    unsigned short* m2s    = (unsigned short*)(wsb + (size_t)OFF_M2S * 4);

    hist     <<<NBLK_BIN, 256, 0, stream>>>(dst, counts);
    scanA    <<<NBLK_SCANA, 256, 0, stream>>>(counts, bsum);
    scanB    <<<1, 1024, 0, stream>>>(bsum);
    scanC    <<<NBLK_SCANA, 256, 0, stream>>>(counts, bsum);
    binpass  <<<NBLK_BIN, 256, 0, stream>>>(src, dst, counts, binned);
    sortpass <<<NBKT, 512, 0, stream>>>(binned, counts, sorted, rowptr, dinv);
    gemm1    <<<G1_BLOCKS, 256, 0, stream>>>(x, W1, dinv, m1s);
    agg1     <<<NBKT, 512, 0, stream>>>(sorted, rowptr, dinv, m1s, b1, W2, m2s);
    agg2     <<<NBKT, 256, 0, stream>>>(sorted, rowptr, dinv, m2s, b2, out);
}